// Round 2
// baseline (7009.892 us; speedup 1.0000x reference)
//
#include <hip/hip_runtime.h>
#include <hip/hip_bf16.h>

// Problem dims
#define BB 256
#define KK 512
#define UU 16
#define PP 64
#define HH 256
#define LL 64
#define THD 128   // 2*P
#define G3 768    // 3*H
#define NT 512    // threads per block (8 waves)

typedef _Float16 half_t;
typedef _Float16 v2h __attribute__((ext_vector_type(2)));

// packed f16 dot2 with fp32 accumulate
__device__ __forceinline__ float fdot2(v2h a, v2h b, float c) {
#if __has_builtin(__builtin_amdgcn_fdot2)
  return __builtin_amdgcn_fdot2(a, b, c, false);
#else
  return fmaf((float)a.x, (float)b.x, fmaf((float)a.y, (float)b.y, c));
#endif
}

__device__ __forceinline__ float sigm(float x) { return 1.f / (1.f + __expf(-x)); }

struct SM {
  alignas(16) half_t wih[G3 * 68];   // W_ih rows padded 64->68 halfs (bank spread)
  alignas(16) float  wlt[80 * 65];   // W_lift transposed [f][j], pitch 65
  alignas(16) float  jmp[UU * PP];   // jump [u][p]
  float b_ih[G3];
  float b_hh[G3];
  float b_lift[LL];
  float b_head[THD];
  float gi[G3];
  float gh[G3];
  alignas(16) float  h[HH];
  alignas(16) half_t h16[HH];
  alignas(16) half_t x16[LL];
  float theta[THD];
  float y[PP];
  float ypre[PP];
  float us[2][UU];
  float dts[2];
};

__global__ __launch_bounds__(NT, 2) void odernn_kernel(
    const float* __restrict__ y0, const float* __restrict__ u_seq,
    const float* __restrict__ dt_seq, const float* __restrict__ W_lift,
    const float* __restrict__ b_lift, const float* __restrict__ W_ih,
    const float* __restrict__ b_ih, const float* __restrict__ W_hh,
    const float* __restrict__ b_hh, const float* __restrict__ W_head,
    const float* __restrict__ b_head, const float* __restrict__ jump,
    float* __restrict__ out_y, float* __restrict__ out_th) {
  __shared__ SM sm;
  const int b = blockIdx.x;
  const int t = threadIdx.x;

  // gg-phase mapping: pair p = t>>1 handles outputs {3p, 3p+1, 3p+2}
  const int p = t >> 1, e = t & 1;
  const int jf = 3 * p + e;   // full-row output for this thread
  const int j2 = 3 * p + 2;   // shared half-row output for the pair
  // head-phase mapping: quad handles one of 128 outputs
  const int hj = t >> 2, hq = t & 3;

  // ---- register-resident weights (packed f16 pairs) ----
  v2h whf[128];  // W_hh row jf (256 halfs)
  v2h wh2[64];   // W_hh row j2, half [128e, 128e+128)
  v2h whd[32];   // W_head row hj, quarter hq (bank-rotated order)
  {
    const float2* w2 = (const float2*)W_hh;
#pragma unroll
    for (int w = 0; w < 128; ++w) {
      float2 f = w2[jf * 128 + w];
      v2h v; v.x = (half_t)f.x; v.y = (half_t)f.y;
      whf[w] = v;
    }
#pragma unroll
    for (int w = 0; w < 64; ++w) {
      float2 f = w2[j2 * 128 + 64 * e + w];
      v2h v; v.x = (half_t)f.x; v.y = (half_t)f.y;
      wh2[w] = v;
    }
    const float2* wh = (const float2*)W_head;
#pragma unroll
    for (int w = 0; w < 32; ++w) {
      int ww = (w + 8 * hq) & 31;           // rotate start per quarter -> conflict-free h reads
      float2 f = wh[hj * 128 + 32 * hq + ww];
      v2h v; v.x = (half_t)f.x; v.y = (half_t)f.y;
      whd[w] = v;
    }
  }

  // ---- LDS init ----
  for (int i = t; i < G3 * 64; i += NT) {
    int r = i >> 6, c = i & 63;
    sm.wih[r * 68 + c] = (half_t)W_ih[i];
  }
  for (int i = t; i < 64 * 80; i += NT) {
    int j = i / 80, f = i - j * 80;
    sm.wlt[f * 65 + j] = W_lift[i];
  }
  for (int i = t; i < UU * PP; i += NT) sm.jmp[i] = jump[i];
  for (int i = t; i < G3; i += NT) { sm.b_ih[i] = b_ih[i]; sm.b_hh[i] = b_hh[i]; }
  if (t < LL) sm.b_lift[t] = b_lift[t];
  if (t < THD) sm.b_head[t] = b_head[t];
  for (int i = t; i < HH; i += NT) { sm.h[i] = 0.f; sm.h16[i] = (half_t)0.f; }
  if (t < PP) sm.y[t] = y0[b * PP + t];
  if (t < UU) sm.us[0][t] = u_seq[(size_t)b * KK * UU + t];
  if (t == UU) sm.dts[0] = dt_seq[(size_t)b * KK];
  __syncthreads();

#pragma unroll 1
  for (int k = 0; k < KK; ++k) {
    const int cb = k & 1;

    // ---- P1: lift (waves 0-3, 4 threads per output) + jump-pre (wave 4) ----
    if (t < 256) {
      const int j = t >> 2, part = t & 3;
      const int f0 = part * 20;
      float acc = 0.f;
#pragma unroll
      for (int c = 0; c < 20; ++c) {
        int f = f0 + c;
        float fv = (f < UU) ? sm.us[cb][f] : sm.y[f - UU];
        acc = fmaf(fv, sm.wlt[f * 65 + j], acc);
      }
      acc += __shfl_xor(acc, 1);
      acc += __shfl_xor(acc, 2);
      if (part == 0) {
        float v = acc + sm.b_lift[j];
        sm.x16[j] = (half_t)(v * sigm(v));   // silu
      }
    } else if (t < 320) {
      const int i = t - 256;
      float acc = sm.y[i];
#pragma unroll
      for (int u = 0; u < UU; ++u) acc = fmaf(sm.us[cb][u], sm.jmp[u * PP + i], acc);
      sm.ypre[i] = acc;                       // y_prev + u_k @ jump
    }
    __syncthreads();

    // ---- P2: gi = W_ih@x + b_ih ; gh = W_hh@h + b_hh (kept separate for n-gate) ----
    {
      float aFh = sm.b_hh[jf], aFi = sm.b_ih[jf];
      float aHh = 0.f, aHi = 0.f;
      const v2h* hp = (const v2h*)sm.h16;    // broadcast reads
      const v2h* xp = (const v2h*)sm.x16;
#pragma unroll
      for (int w = 0; w < 128; ++w) aFh = fdot2(whf[w], hp[w], aFh);
      const v2h* hp2 = hp + 64 * e;
#pragma unroll
      for (int w = 0; w < 64; ++w) aHh = fdot2(wh2[w], hp2[w], aHh);
      const v2h* wif = (const v2h*)&sm.wih[jf * 68];
#pragma unroll
      for (int w = 0; w < 32; ++w) aFi = fdot2(wif[w], xp[w], aFi);
      const v2h* wih2 = (const v2h*)&sm.wih[j2 * 68] + 16 * e;
      const v2h* xp2 = xp + 16 * e;
#pragma unroll
      for (int w = 0; w < 16; ++w) aHi = fdot2(wih2[w], xp2[w], aHi);
      aHh += __shfl_xor(aHh, 1);
      aHi += __shfl_xor(aHi, 1);
      sm.gh[jf] = aFh;
      sm.gi[jf] = aFi;
      if (e == 0) {
        sm.gh[j2] = aHh + sm.b_hh[j2];
        sm.gi[j2] = aHi + sm.b_ih[j2];
      }
    }
    __syncthreads();

    // ---- P3: GRU gates (waves 0-3) + prefetch next u/dt (wave 4) ----
    if (t < 256) {
      float r = sigm(sm.gi[t] + sm.gh[t]);
      float z = sigm(sm.gi[256 + t] + sm.gh[256 + t]);
      float pre = sm.gi[512 + t] + r * sm.gh[512 + t];
      float n = 2.f * sigm(2.f * pre) - 1.f;  // tanh
      float hn = (1.f - z) * n + z * sm.h[t];
      sm.h[t] = hn;
      sm.h16[t] = (half_t)hn;
    } else if (k + 1 < KK && t >= 256 && t < 256 + UU) {
      sm.us[cb ^ 1][t - 256] =
          u_seq[(size_t)b * KK * UU + (size_t)(k + 1) * UU + (t - 256)];
    } else if (k + 1 < KK && t == 256 + UU) {
      sm.dts[cb ^ 1] = dt_seq[(size_t)b * KK + (k + 1)];
    }
    __syncthreads();

    // ---- P4: head -> theta (4 threads per output) ----
    {
      float acc = 0.f;
      const v2h* hp = (const v2h*)sm.h16 + 32 * hq;
#pragma unroll
      for (int w = 0; w < 32; ++w) {
        int ww = (w + 8 * hq) & 31;          // matches rotated whd load order
        acc = fdot2(whd[w], hp[ww], acc);
      }
      acc += __shfl_xor(acc, 1);
      acc += __shfl_xor(acc, 2);
      if (hq == 0) {
        float raw = acc + sm.b_head[hj];
        sm.theta[hj] = 0.001f + 1.999f * sigm(raw);
      }
    }
    __syncthreads();

    // ---- P5: RK4 + clamp + global stores (f32 outputs!) ----
    if (t < PP) {
      float a = sm.theta[t], dr = sm.theta[PP + t];
      float yv = sm.ypre[t];
      float hdt = sm.dts[cb];
      float k1 = dr - a * yv;
      float k2 = dr - a * fmaf(0.5f * hdt, k1, yv);
      float k3 = dr - a * fmaf(0.5f * hdt, k2, yv);
      float k4 = dr - a * fmaf(hdt, k3, yv);
      yv = yv + (hdt * (1.f / 6.f)) * (k1 + 2.f * k2 + 2.f * k3 + k4);
      yv = fmaxf(yv, 0.f);
      sm.y[t] = yv;
      out_y[(size_t)b * KK * PP + (size_t)k * PP + t] = yv;
    } else if (t < 64 + THD) {
      int j = t - 64;
      out_th[(size_t)b * KK * THD + (size_t)k * THD + j] = sm.theta[j];
    }
    __syncthreads();
  }
}

extern "C" void kernel_launch(void* const* d_in, const int* in_sizes, int n_in,
                              void* d_out, int out_size, void* d_ws, size_t ws_size,
                              hipStream_t stream) {
  (void)in_sizes; (void)n_in; (void)d_ws; (void)ws_size; (void)out_size;
  const float* y0     = (const float*)d_in[0];
  const float* u_seq  = (const float*)d_in[1];
  const float* dt_seq = (const float*)d_in[2];
  const float* W_lift = (const float*)d_in[3];
  const float* b_lift = (const float*)d_in[4];
  const float* W_ih   = (const float*)d_in[5];
  const float* b_ih   = (const float*)d_in[6];
  const float* W_hh   = (const float*)d_in[7];
  const float* b_hh   = (const float*)d_in[8];
  const float* W_head = (const float*)d_in[9];
  const float* b_head = (const float*)d_in[10];
  const float* jump   = (const float*)d_in[11];
  float* out  = (float*)d_out;
  float* outy = out;
  float* outt = out + (size_t)BB * KK * PP;
  odernn_kernel<<<dim3(BB), dim3(NT), 0, stream>>>(
      y0, u_seq, dt_seq, W_lift, b_lift, W_ih, b_ih, W_hh, b_hh,
      W_head, b_head, jump, outy, outt);
}

// Round 3
// 6183.474 us; speedup vs baseline: 1.1336x; 1.1336x over previous
//
#include <hip/hip_runtime.h>
#include <hip/hip_bf16.h>

// Problem dims
#define BB 256
#define KK 512
#define UU 16
#define PP 64
#define HH 256
#define LL 64
#define THD 128   // 2*P
#define G3 768    // 3*H
#define NT 512    // threads per block (8 waves)
#define WIH_P 66  // W_ih row pitch in halfs (33 dwords -> 2 lanes/bank, free)

typedef _Float16 half_t;
typedef _Float16 v2h __attribute__((ext_vector_type(2)));

// packed f16 dot2 with fp32 accumulate
__device__ __forceinline__ float fdot2(v2h a, v2h b, float c) {
#if __has_builtin(__builtin_amdgcn_fdot2)
  return __builtin_amdgcn_fdot2(a, b, c, false);
#else
  return fmaf((float)a.x, (float)b.x, fmaf((float)a.y, (float)b.y, c));
#endif
}

__device__ __forceinline__ float sigm(float x) { return 1.f / (1.f + __expf(-x)); }

struct SM {
  alignas(16) half_t wih[G3 * WIH_P];  // W_ih rows padded 64->66 halfs
  alignas(16) float  wlt[80 * 65];     // W_lift transposed [f][j], pitch 65
  alignas(16) float  jmp[UU * PP];     // jump [u][p]
  float b_ih[G3];
  float b_hh[G3];
  float b_lift[LL];
  float b_head[THD];
  float gi[G3];
  float gh[G3];
  alignas(16) float  h[HH];
  alignas(16) half_t h16[HH];
  alignas(16) half_t x16[LL];
  float theta[THD];
  float y[PP];
  float ypre[PP];
  float us[2][UU];
  float dts[2];
};

__attribute__((amdgpu_waves_per_eu(2, 2)))
__global__ __launch_bounds__(NT) void odernn_kernel(
    const float* __restrict__ y0, const float* __restrict__ u_seq,
    const float* __restrict__ dt_seq, const float* __restrict__ W_lift,
    const float* __restrict__ b_lift, const float* __restrict__ W_ih,
    const float* __restrict__ b_ih, const float* __restrict__ W_hh,
    const float* __restrict__ b_hh, const float* __restrict__ W_head,
    const float* __restrict__ b_head, const float* __restrict__ jump,
    float* __restrict__ out_y, float* __restrict__ out_th) {
  __shared__ SM sm;
  const int b = blockIdx.x;
  const int t = threadIdx.x;

  // gg-phase mapping: pair p = t>>1 handles outputs {3p, 3p+1, 3p+2}
  const int p = t >> 1, e = t & 1;
  const int jf = 3 * p + e;   // full-row output for this thread
  const int j2 = 3 * p + 2;   // shared half-row output for the pair
  // head-phase mapping: quad handles one of 128 outputs
  const int hj = t >> 2, hq = t & 3;

  // ---- register-resident weights (packed f16 pairs) ----
  v2h whf[128];  // W_hh row jf (256 halfs)
  v2h wh2[64];   // W_hh row j2, half [128e, 128e+128)
  v2h whd[32];   // W_head row hj, quarter hq (bank-rotated order)
  {
    const float2* w2 = (const float2*)W_hh;
#pragma unroll
    for (int w = 0; w < 128; ++w) {
      float2 f = w2[jf * 128 + w];
      v2h v; v.x = (half_t)f.x; v.y = (half_t)f.y;
      whf[w] = v;
    }
#pragma unroll
    for (int w = 0; w < 64; ++w) {
      float2 f = w2[j2 * 128 + 64 * e + w];
      v2h v; v.x = (half_t)f.x; v.y = (half_t)f.y;
      wh2[w] = v;
    }
    const float2* wh = (const float2*)W_head;
#pragma unroll
    for (int w = 0; w < 32; ++w) {
      int ww = (w + 8 * hq) & 31;           // rotate start per quarter
      float2 f = wh[hj * 128 + 32 * hq + ww];
      v2h v; v.x = (half_t)f.x; v.y = (half_t)f.y;
      whd[w] = v;
    }
  }

  // ---- LDS init ----
  for (int i = t; i < G3 * 64; i += NT) {
    int r = i >> 6, c = i & 63;
    sm.wih[r * WIH_P + c] = (half_t)W_ih[i];
  }
  for (int i = t; i < 64 * 80; i += NT) {
    int j = i / 80, f = i - j * 80;
    sm.wlt[f * 65 + j] = W_lift[i];
  }
  for (int i = t; i < UU * PP; i += NT) sm.jmp[i] = jump[i];
  for (int i = t; i < G3; i += NT) { sm.b_ih[i] = b_ih[i]; sm.b_hh[i] = b_hh[i]; }
  if (t < LL) sm.b_lift[t] = b_lift[t];
  if (t < THD) sm.b_head[t] = b_head[t];
  for (int i = t; i < HH; i += NT) { sm.h[i] = 0.f; sm.h16[i] = (half_t)0.f; }
  if (t < PP) sm.y[t] = y0[b * PP + t];
  if (t < UU) sm.us[0][t] = u_seq[(size_t)b * KK * UU + t];
  if (t == UU) sm.dts[0] = dt_seq[(size_t)b * KK];
  __syncthreads();

#pragma unroll 1
  for (int k = 0; k < KK; ++k) {
    const int cb = k & 1;

    // ---- P1: lift (waves 0-3, 4 threads per output) + jump-pre (wave 4) ----
    if (t < 256) {
      const int j = t >> 2, part = t & 3;
      const int f0 = part * 20;
      float acc = 0.f;
#pragma unroll
      for (int c = 0; c < 20; ++c) {
        int f = f0 + c;
        float fv = (f < UU) ? sm.us[cb][f] : sm.y[f - UU];
        acc = fmaf(fv, sm.wlt[f * 65 + j], acc);
      }
      acc += __shfl_xor(acc, 1);
      acc += __shfl_xor(acc, 2);
      if (part == 0) {
        float v = acc + sm.b_lift[j];
        sm.x16[j] = (half_t)(v * sigm(v));   // silu
      }
    } else if (t < 320) {
      const int i = t - 256;
      float acc = sm.y[i];
#pragma unroll
      for (int u = 0; u < UU; ++u) acc = fmaf(sm.us[cb][u], sm.jmp[u * PP + i], acc);
      sm.ypre[i] = acc;                       // y_prev + u_k @ jump
    }
    __syncthreads();

    // ---- P2: gi = W_ih@x + b_ih ; gh = W_hh@h + b_hh (kept separate for n-gate) ----
    {
      const v2h* hp = (const v2h*)sm.h16;    // broadcast reads
      const v2h* xp = (const v2h*)sm.x16;
      // main W_hh row: 4 parallel accumulator chains
      float a0 = 0.f, a1 = 0.f, a2 = 0.f, a3 = 0.f;
#pragma unroll
      for (int w = 0; w < 32; ++w) {
        a0 = fdot2(whf[4 * w + 0], hp[4 * w + 0], a0);
        a1 = fdot2(whf[4 * w + 1], hp[4 * w + 1], a1);
        a2 = fdot2(whf[4 * w + 2], hp[4 * w + 2], a2);
        a3 = fdot2(whf[4 * w + 3], hp[4 * w + 3], a3);
      }
      float aFh = sm.b_hh[jf] + ((a0 + a1) + (a2 + a3));
      // shared row j2: 2 parallel chains
      const v2h* hp2 = hp + 64 * e;
      float c0 = 0.f, c1 = 0.f;
#pragma unroll
      for (int w = 0; w < 32; ++w) {
        c0 = fdot2(wh2[2 * w + 0], hp2[2 * w + 0], c0);
        c1 = fdot2(wh2[2 * w + 1], hp2[2 * w + 1], c1);
      }
      float aHh = c0 + c1;
      // W_ih from LDS (pitch 66 halfs -> conflict-free)
      const v2h* wif = (const v2h*)&sm.wih[jf * WIH_P];
      float d0 = 0.f, d1 = 0.f;
#pragma unroll
      for (int w = 0; w < 16; ++w) {
        d0 = fdot2(wif[2 * w + 0], xp[2 * w + 0], d0);
        d1 = fdot2(wif[2 * w + 1], xp[2 * w + 1], d1);
      }
      float aFi = sm.b_ih[jf] + d0 + d1;
      const v2h* wih2 = (const v2h*)&sm.wih[j2 * WIH_P] + 16 * e;
      const v2h* xp2 = xp + 16 * e;
      float aHi = 0.f;
#pragma unroll
      for (int w = 0; w < 16; ++w) aHi = fdot2(wih2[w], xp2[w], aHi);
      aHh += __shfl_xor(aHh, 1);
      aHi += __shfl_xor(aHi, 1);
      sm.gh[jf] = aFh;
      sm.gi[jf] = aFi;
      if (e == 0) {
        sm.gh[j2] = aHh + sm.b_hh[j2];
        sm.gi[j2] = aHi + sm.b_ih[j2];
      }
    }
    __syncthreads();

    // ---- P3: GRU gates (waves 0-3) + prefetch next u/dt (wave 4) ----
    if (t < 256) {
      float r = sigm(sm.gi[t] + sm.gh[t]);
      float z = sigm(sm.gi[256 + t] + sm.gh[256 + t]);
      float pre = sm.gi[512 + t] + r * sm.gh[512 + t];
      float n = 2.f * sigm(2.f * pre) - 1.f;  // tanh
      float hn = (1.f - z) * n + z * sm.h[t];
      sm.h[t] = hn;
      sm.h16[t] = (half_t)hn;
    } else if (k + 1 < KK && t >= 256 && t < 256 + UU) {
      sm.us[cb ^ 1][t - 256] =
          u_seq[(size_t)b * KK * UU + (size_t)(k + 1) * UU + (t - 256)];
    } else if (k + 1 < KK && t == 256 + UU) {
      sm.dts[cb ^ 1] = dt_seq[(size_t)b * KK + (k + 1)];
    }
    __syncthreads();

    // ---- P4: head -> theta (4 threads per output) ----
    {
      float acc = 0.f;
      const v2h* hp = (const v2h*)sm.h16 + 32 * hq;
#pragma unroll
      for (int w = 0; w < 32; ++w) {
        int ww = (w + 8 * hq) & 31;          // matches rotated whd load order
        acc = fdot2(whd[w], hp[ww], acc);
      }
      acc += __shfl_xor(acc, 1);
      acc += __shfl_xor(acc, 2);
      if (hq == 0) {
        float raw = acc + sm.b_head[hj];
        sm.theta[hj] = 0.001f + 1.999f * sigm(raw);
      }
    }
    __syncthreads();

    // ---- P5: RK4 + clamp + global stores (f32 outputs) ----
    if (t < PP) {
      float a = sm.theta[t], dr = sm.theta[PP + t];
      float yv = sm.ypre[t];
      float hdt = sm.dts[cb];
      float k1 = dr - a * yv;
      float k2 = dr - a * fmaf(0.5f * hdt, k1, yv);
      float k3 = dr - a * fmaf(0.5f * hdt, k2, yv);
      float k4 = dr - a * fmaf(hdt, k3, yv);
      yv = yv + (hdt * (1.f / 6.f)) * (k1 + 2.f * k2 + 2.f * k3 + k4);
      yv = fmaxf(yv, 0.f);
      sm.y[t] = yv;
      out_y[(size_t)b * KK * PP + (size_t)k * PP + t] = yv;
    } else if (t < 64 + THD) {
      int j = t - 64;
      out_th[(size_t)b * KK * THD + (size_t)k * THD + j] = sm.theta[j];
    }
    __syncthreads();
  }
}

extern "C" void kernel_launch(void* const* d_in, const int* in_sizes, int n_in,
                              void* d_out, int out_size, void* d_ws, size_t ws_size,
                              hipStream_t stream) {
  (void)in_sizes; (void)n_in; (void)d_ws; (void)ws_size; (void)out_size;
  const float* y0     = (const float*)d_in[0];
  const float* u_seq  = (const float*)d_in[1];
  const float* dt_seq = (const float*)d_in[2];
  const float* W_lift = (const float*)d_in[3];
  const float* b_lift = (const float*)d_in[4];
  const float* W_ih   = (const float*)d_in[5];
  const float* b_ih   = (const float*)d_in[6];
  const float* W_hh   = (const float*)d_in[7];
  const float* b_hh   = (const float*)d_in[8];
  const float* W_head = (const float*)d_in[9];
  const float* b_head = (const float*)d_in[10];
  const float* jump   = (const float*)d_in[11];
  float* out  = (float*)d_out;
  float* outy = out;
  float* outt = out + (size_t)BB * KK * PP;
  odernn_kernel<<<dim3(BB), dim3(NT), 0, stream>>>(
      y0, u_seq, dt_seq, W_lift, b_lift, W_ih, b_ih, W_hh, b_hh,
      W_head, b_head, jump, outy, outt);
}

// Round 5
// 4106.323 us; speedup vs baseline: 1.7071x; 1.5058x over previous
//
#include <hip/hip_runtime.h>
#include <hip/hip_bf16.h>

// Problem dims
#define BB 256
#define KK 512
#define UU 16
#define PP 64
#define HH 256
#define LL 64
#define THD 128   // 2*P
#define G3 768    // 3*H
#define NT 512    // threads per block (8 waves)
#define WIH_P 66  // W_ih row pitch in halfs (33 dwords -> banks spread, v2h aligned)

typedef _Float16 half_t;
typedef _Float16 v2h __attribute__((ext_vector_type(2)));
typedef _Float16 v8h __attribute__((ext_vector_type(8)));

#define P2H(v, i) __builtin_shufflevector((v), (v), 2 * (i), 2 * (i) + 1)

#define REP8(M)  M(0) M(1) M(2) M(3) M(4) M(5) M(6) M(7)
#define REP16(M) REP8(M) M(8) M(9) M(10) M(11) M(12) M(13) M(14) M(15)
#define REP32(M) REP16(M) M(16) M(17) M(18) M(19) M(20) M(21) M(22) M(23) \
                 M(24) M(25) M(26) M(27) M(28) M(29) M(30) M(31)

// packed f16 dot2 with fp32 accumulate
__device__ __forceinline__ float fdot2(v2h a, v2h b, float c) {
#if __has_builtin(__builtin_amdgcn_fdot2)
  return __builtin_amdgcn_fdot2(a, b, c, false);
#else
  return fmaf((float)a.x, (float)b.x, fmaf((float)a.y, (float)b.y, c));
#endif
}

__device__ __forceinline__ float sigm(float x) { return 1.f / (1.f + __expf(-x)); }

// load float2 from global, convert to packed f16 pair
__device__ __forceinline__ v2h ld2(const float2* p) {
  float2 f = *p;
  v2h v; v.x = (half_t)f.x; v.y = (half_t)f.y;
  return v;
}

struct SM {
  alignas(16) half_t wih[G3 * WIH_P];  // W_ih rows, pitch 66 halfs
  alignas(16) float  wlt[80 * 65];     // W_lift transposed [f][j], pitch 65
  alignas(16) float  jmp[UU * PP];     // jump [u][p]
  float b_ih[G3];
  float b_hh[G3];
  float b_lift[LL];
  float b_head[THD];
  float gi[G3];
  float gh[G3];
  alignas(16) float  h[HH];
  alignas(16) half_t h16[HH];
  alignas(16) half_t x16[LL];
  float theta[THD];
  float y[PP];
  float ypre[PP];
  float us[2][UU];
  float dts[2];
};

__global__
__attribute__((amdgpu_flat_work_group_size(NT, NT), amdgpu_waves_per_eu(2, 2)))
void odernn_kernel(
    const float* __restrict__ y0, const float* __restrict__ u_seq,
    const float* __restrict__ dt_seq, const float* __restrict__ W_lift,
    const float* __restrict__ b_lift, const float* __restrict__ W_ih,
    const float* __restrict__ b_ih, const float* __restrict__ W_hh,
    const float* __restrict__ b_hh, const float* __restrict__ W_head,
    const float* __restrict__ b_head, const float* __restrict__ jump,
    float* __restrict__ out_y, float* __restrict__ out_th) {
  __shared__ SM sm;
  const int b = blockIdx.x;
  const int t = threadIdx.x;

  // gg-phase mapping: pair p = t>>1 handles rows {3p, 3p+1, 3p+2}
  const int p = t >> 1, e = t & 1;
  const int jf = 3 * p + e;   // full-row output for this thread
  const int j2 = 3 * p + 2;   // shared half-row output for the pair
  // head-phase mapping: quad handles one of 128 outputs
  const int hj = t >> 2, hq = t & 3;

  // ---- register-resident weights: 224 NAMED v2h values (no arrays -> no
  // scratch allocas; rule #20 / SROA). Live for the whole kernel. ----
  const float2* w2 = (const float2*)W_hh;
  const float2* wh = (const float2*)W_head;
  const int jb  = jf * 128;            // float2 index of W_hh row jf
  const int j2b = j2 * 128 + 64 * e;   // this thread's half of row j2
  const int hb  = hj * 128 + 32 * hq;  // this thread's quarter of W_head row hj

#define DECL_WF(q) v2h wfa##q = ld2(w2 + jb + 4 * q),     \
                       wfb##q = ld2(w2 + jb + 4 * q + 1), \
                       wfc##q = ld2(w2 + jb + 4 * q + 2), \
                       wfd##q = ld2(w2 + jb + 4 * q + 3);
  REP32(DECL_WF)
#define DECL_WG(q) v2h wga##q = ld2(w2 + j2b + 4 * q),     \
                       wgb##q = ld2(w2 + j2b + 4 * q + 1), \
                       wgc##q = ld2(w2 + j2b + 4 * q + 2), \
                       wgd##q = ld2(w2 + j2b + 4 * q + 3);
  REP16(DECL_WG)
#define DECL_WD(q) v2h wda##q = ld2(wh + hb + 4 * q),     \
                       wdb##q = ld2(wh + hb + 4 * q + 1), \
                       wdc##q = ld2(wh + hb + 4 * q + 2), \
                       wdd##q = ld2(wh + hb + 4 * q + 3);
  REP8(DECL_WD)

  // ---- LDS init ----
  for (int i = t; i < G3 * 64; i += NT) {
    int r = i >> 6, c = i & 63;
    sm.wih[r * WIH_P + c] = (half_t)W_ih[i];
  }
  for (int i = t; i < 64 * 80; i += NT) {
    int j = i / 80, f = i - j * 80;
    sm.wlt[f * 65 + j] = W_lift[i];
  }
  for (int i = t; i < UU * PP; i += NT) sm.jmp[i] = jump[i];
  for (int i = t; i < G3; i += NT) { sm.b_ih[i] = b_ih[i]; sm.b_hh[i] = b_hh[i]; }
  if (t < LL) sm.b_lift[t] = b_lift[t];
  if (t < THD) sm.b_head[t] = b_head[t];
  for (int i = t; i < HH; i += NT) { sm.h[i] = 0.f; sm.h16[i] = (half_t)0.f; }
  if (t < PP) sm.y[t] = y0[b * PP + t];
  if (t < UU) sm.us[0][t] = u_seq[(size_t)b * KK * UU + t];
  if (t == UU) sm.dts[0] = dt_seq[(size_t)b * KK];
  __syncthreads();

#pragma unroll 1
  for (int k = 0; k < KK; ++k) {
    const int cb = k & 1;

    // ---- P1: lift (waves 0-3, 4 threads per output) + jump-pre (wave 4) ----
    if (t < 256) {
      const int j = t >> 2, part = t & 3;
      const int f0 = part * 20;
      float acc = 0.f;
#pragma unroll
      for (int c = 0; c < 20; ++c) {
        int f = f0 + c;
        float fv = (f < UU) ? sm.us[cb][f] : sm.y[f - UU];
        acc = fmaf(fv, sm.wlt[f * 65 + j], acc);
      }
      acc += __shfl_xor(acc, 1);
      acc += __shfl_xor(acc, 2);
      if (part == 0) {
        float v = acc + sm.b_lift[j];
        sm.x16[j] = (half_t)(v * sigm(v));   // silu
      }
    } else if (t < 320) {
      const int i = t - 256;
      float acc = sm.y[i];
#pragma unroll
      for (int u = 0; u < UU; ++u) acc = fmaf(sm.us[cb][u], sm.jmp[u * PP + i], acc);
      sm.ypre[i] = acc;                       // y_prev + u_k @ jump
    }
    __syncthreads();

    // ---- P2: gi = W_ih@x + b_ih ; gh = W_hh@h + b_hh ----
    {
      const v8h* hp8 = (const v8h*)sm.h16;   // lane-invariant -> LDS broadcast
      float a0 = 0.f, a1 = 0.f, a2 = 0.f, a3 = 0.f;
#define DOT_WF(q) { v8h hv = hp8[q];                  \
      a0 = fdot2(wfa##q, P2H(hv, 0), a0);             \
      a1 = fdot2(wfb##q, P2H(hv, 1), a1);             \
      a2 = fdot2(wfc##q, P2H(hv, 2), a2);             \
      a3 = fdot2(wfd##q, P2H(hv, 3), a3); }
      REP32(DOT_WF)
      float aFh = sm.b_hh[jf] + ((a0 + a1) + (a2 + a3));

      const v8h* hq8 = hp8 + 16 * e;         // 2 addrs/wave -> free
      float b0 = 0.f, b1 = 0.f;
#define DOT_WG(q) { v8h hv = hq8[q];                  \
      b0 = fdot2(wga##q, P2H(hv, 0), b0);             \
      b1 = fdot2(wgb##q, P2H(hv, 1), b1);             \
      b0 = fdot2(wgc##q, P2H(hv, 2), b0);             \
      b1 = fdot2(wgd##q, P2H(hv, 3), b1); }
      REP16(DOT_WG)
      float aHh = b0 + b1;

      // W_ih from LDS as v2h (pitch 66 halfs = 33 dwords, banks spread)
      const v2h* wif = (const v2h*)sm.wih + jf * 33;
      const v2h* xp  = (const v2h*)sm.x16;
      float d0 = 0.f, d1 = 0.f;
#pragma unroll
      for (int w = 0; w < 16; ++w) {
        d0 = fdot2(wif[2 * w + 0], xp[2 * w + 0], d0);
        d1 = fdot2(wif[2 * w + 1], xp[2 * w + 1], d1);
      }
      float aFi = sm.b_ih[jf] + d0 + d1;
      const v2h* wif2 = (const v2h*)sm.wih + j2 * 33 + 16 * e;
      const v2h* xq   = xp + 16 * e;
      float aHi = 0.f;
#pragma unroll
      for (int w = 0; w < 16; ++w) aHi = fdot2(wif2[w], xq[w], aHi);

      aHh += __shfl_xor(aHh, 1);
      aHi += __shfl_xor(aHi, 1);
      sm.gh[jf] = aFh;
      sm.gi[jf] = aFi;
      if (e == 0) {
        sm.gh[j2] = aHh + sm.b_hh[j2];
        sm.gi[j2] = aHi + sm.b_ih[j2];
      }
    }
    __syncthreads();

    // ---- P3: GRU gates (waves 0-3) + prefetch next u/dt (wave 4) ----
    if (t < 256) {
      float r = sigm(sm.gi[t] + sm.gh[t]);
      float z = sigm(sm.gi[256 + t] + sm.gh[256 + t]);
      float pre = sm.gi[512 + t] + r * sm.gh[512 + t];
      float n = 2.f * sigm(2.f * pre) - 1.f;  // tanh
      float hn = (1.f - z) * n + z * sm.h[t];
      sm.h[t] = hn;
      sm.h16[t] = (half_t)hn;
    } else if (k + 1 < KK && t >= 256 && t < 256 + UU) {
      sm.us[cb ^ 1][t - 256] =
          u_seq[(size_t)b * KK * UU + (size_t)(k + 1) * UU + (t - 256)];
    } else if (k + 1 < KK && t == 256 + UU) {
      sm.dts[cb ^ 1] = dt_seq[(size_t)b * KK + (k + 1)];
    }
    __syncthreads();

    // ---- P4: head -> theta (4 threads per output) ----
    {
      const v8h* hp8q = (const v8h*)sm.h16 + 8 * hq;  // 4 addrs/wave: ~free
      float c0 = 0.f, c1 = 0.f, c2 = 0.f, c3 = 0.f;
#define DOT_WD(q) { v8h hv = hp8q[q];                 \
      c0 = fdot2(wda##q, P2H(hv, 0), c0);             \
      c1 = fdot2(wdb##q, P2H(hv, 1), c1);             \
      c2 = fdot2(wdc##q, P2H(hv, 2), c2);             \
      c3 = fdot2(wdd##q, P2H(hv, 3), c3); }
      REP8(DOT_WD)
      float acc = (c0 + c1) + (c2 + c3);
      acc += __shfl_xor(acc, 1);
      acc += __shfl_xor(acc, 2);
      if (hq == 0) {
        float raw = acc + sm.b_head[hj];
        sm.theta[hj] = 0.001f + 1.999f * sigm(raw);
      }
    }
    __syncthreads();

    // ---- P5: RK4 + clamp + global stores (f32 outputs) ----
    if (t < PP) {
      float a = sm.theta[t], dr = sm.theta[PP + t];
      float yv = sm.ypre[t];
      float hdt = sm.dts[cb];
      float k1 = dr - a * yv;
      float k2 = dr - a * fmaf(0.5f * hdt, k1, yv);
      float k3 = dr - a * fmaf(0.5f * hdt, k2, yv);
      float k4 = dr - a * fmaf(hdt, k3, yv);
      yv = yv + (hdt * (1.f / 6.f)) * (k1 + 2.f * k2 + 2.f * k3 + k4);
      yv = fmaxf(yv, 0.f);
      sm.y[t] = yv;
      out_y[(size_t)b * KK * PP + (size_t)k * PP + t] = yv;
    } else if (t < 64 + THD) {
      int j = t - 64;
      out_th[(size_t)b * KK * THD + (size_t)k * THD + j] = sm.theta[j];
    }
    __syncthreads();
  }
}

extern "C" void kernel_launch(void* const* d_in, const int* in_sizes, int n_in,
                              void* d_out, int out_size, void* d_ws, size_t ws_size,
                              hipStream_t stream) {
  (void)in_sizes; (void)n_in; (void)d_ws; (void)ws_size; (void)out_size;
  const float* y0     = (const float*)d_in[0];
  const float* u_seq  = (const float*)d_in[1];
  const float* dt_seq = (const float*)d_in[2];
  const float* W_lift = (const float*)d_in[3];
  const float* b_lift = (const float*)d_in[4];
  const float* W_ih   = (const float*)d_in[5];
  const float* b_ih   = (const float*)d_in[6];
  const float* W_hh   = (const float*)d_in[7];
  const float* b_hh   = (const float*)d_in[8];
  const float* W_head = (const float*)d_in[9];
  const float* b_head = (const float*)d_in[10];
  const float* jump   = (const float*)d_in[11];
  float* out  = (float*)d_out;
  float* outy = out;
  float* outt = out + (size_t)BB * KK * PP;
  odernn_kernel<<<dim3(BB), dim3(NT), 0, stream>>>(
      y0, u_seq, dt_seq, W_lift, b_lift, W_ih, b_ih, W_hh, b_hh,
      W_head, b_head, jump, outy, outt);
}